// Round 5
// baseline (492.263 us; speedup 1.0000x reference)
//
#include <hip/hip_runtime.h>

typedef __bf16 bf16_t;
typedef bf16_t bf16x4v __attribute__((ext_vector_type(4)));
typedef bf16_t bf16x8v __attribute__((ext_vector_type(8)));
typedef float f32x4 __attribute__((ext_vector_type(4)));

// async global->LDS, 16B per lane (dest = wave-uniform base + lane*16)
__device__ __forceinline__ void gl_lds16(const void* g, void* l) {
  __builtin_amdgcn_global_load_lds((__attribute__((address_space(1))) void*)g,
                                   (__attribute__((address_space(3))) void*)l,
                                   16, 0, 0);
}

__device__ __forceinline__ float fast_silu(float x) {
  return x / (1.f + __expf(-x));
}

// ---------------- one-shot f32 -> bf16 conversion of all 6 tensors ----------------
// segment boundaries in float4 units:
// h 1048576 | gup 4194304 | dwn 2097152 | sg 524288 | su 524288 | sd 524288
__global__ __launch_bounds__(256)
void cvt_all_kernel(const float* __restrict__ h, const float* __restrict__ gup,
                    const float* __restrict__ dwn, const float* __restrict__ sg,
                    const float* __restrict__ su, const float* __restrict__ sd,
                    bf16_t* __restrict__ h_bf, bf16_t* __restrict__ gup_bf,
                    bf16_t* __restrict__ dwn_bf, bf16_t* __restrict__ sg_bf,
                    bf16_t* __restrict__ su_bf, bf16_t* __restrict__ sd_bf) {
  int i = blockIdx.x * 256 + threadIdx.x;
  const int stride = gridDim.x * 256;
  for (; i < 8912896; i += stride) {
    const float4* src; bf16x4v* dst; int off;
    if (i < 1048576)      { src = (const float4*)h;   dst = (bf16x4v*)h_bf;   off = i; }
    else if (i < 5242880) { src = (const float4*)gup; dst = (bf16x4v*)gup_bf; off = i - 1048576; }
    else if (i < 7340032) { src = (const float4*)dwn; dst = (bf16x4v*)dwn_bf; off = i - 5242880; }
    else if (i < 7864320) { src = (const float4*)sg;  dst = (bf16x4v*)sg_bf;  off = i - 7340032; }
    else if (i < 8388608) { src = (const float4*)su;  dst = (bf16x4v*)su_bf;  off = i - 7864320; }
    else                  { src = (const float4*)sd;  dst = (bf16x4v*)sd_bf;  off = i - 8388608; }
    float4 v = src[off];
    bf16x4v o;
    o[0] = (bf16_t)v.x; o[1] = (bf16_t)v.y; o[2] = (bf16_t)v.z; o[3] = (bf16_t)v.w;
    dst[off] = o;
  }
}

// ---------------- R1: per-token logits + top-4 + shared gate (atomic-free) --------
__global__ __launch_bounds__(256)
void router_topk_kernel(const float* __restrict__ h, const float* __restrict__ rw,
                        const float* __restrict__ segw, float* __restrict__ gsig,
                        int* __restrict__ tokTopI, float* __restrict__ tokTopW) {
  const int t = threadIdx.x;
  const int lane = t & 63;
  const int wid = t >> 6;
  const int grp = lane >> 4;
  const int e = lane & 15;
  const int tok = blockIdx.x * 16 + wid * 4 + grp;

  const float4* h4 = (const float4*)(h + (size_t)tok * 1024);
  const float4* rw4 = (const float4*)(rw + (size_t)e * 1024);
  const float4* sg4 = (const float4*)segw;

  float s = 0.f, ss = 0.f;
  #pragma unroll 8
  for (int c = 0; c < 256; ++c) {
    float4 hv = h4[c];
    float4 wv = rw4[c];
    s += hv.x * wv.x + hv.y * wv.y + hv.z * wv.z + hv.w * wv.w;
    if ((c & 15) == e) {
      float4 gv = sg4[c];
      ss += hv.x * gv.x + hv.y * gv.y + hv.z * gv.z + hv.w * gv.w;
    }
  }
  #pragma unroll
  for (int m = 1; m <= 8; m <<= 1) ss += __shfl_xor(ss, m);
  float mx = s;
  #pragma unroll
  for (int m = 1; m <= 8; m <<= 1) mx = fmaxf(mx, __shfl_xor(mx, m));
  float p = expf(s - mx);

  float pc = p;
  float tsum = 0.f;
  float myw = 0.f; int myi = 0;
  #pragma unroll
  for (int r = 0; r < 4; ++r) {
    float v = pc; int idx = e;
    #pragma unroll
    for (int m = 1; m <= 8; m <<= 1) {
      float ov = __shfl_xor(v, m); int oi = __shfl_xor(idx, m);
      if (ov > v || (ov == v && oi < idx)) { v = ov; idx = oi; }
    }
    tsum += v;
    if (e == r) { myi = idx; myw = v; }
    if (e == idx) pc = -1.f;
  }
  if (e < 4) {
    tokTopI[tok * 4 + e] = myi;
    tokTopW[tok * 4 + e] = myw / tsum;
  }
  if (e == 0) gsig[tok] = 1.f / (1.f + expf(-ss));
}

// ---------------- R2: per-expert compact lists + per-assignment positions ---------
__global__ __launch_bounds__(256)
void build_lists_kernel(const int* __restrict__ tokTopI,
                        const float* __restrict__ tokTopW,
                        int* __restrict__ cnt, int* __restrict__ toklist,
                        float* __restrict__ wlist, int* __restrict__ posOf) {
  const int e = blockIdx.x;
  const int t = threadIdx.x;
  const int lane = t & 63;
  const int wid = t >> 6;
  __shared__ int base;
  __shared__ int wsum[4];
  if (t == 0) base = 0;
  __syncthreads();

  for (int chunk = 0; chunk < 16; ++chunk) {
    const int i0 = chunk * 1024 + t * 4;
    int4 ti = *(const int4*)&tokTopI[i0];
    const bool f0 = ti.x == e, f1 = ti.y == e, f2 = ti.z == e, f3 = ti.w == e;
    const int c = (int)f0 + (int)f1 + (int)f2 + (int)f3;
    int inc = c;
    #pragma unroll
    for (int m = 1; m <= 32; m <<= 1) {
      int o = __shfl_up(inc, m);
      if (lane >= m) inc += o;
    }
    const int lanePre = inc - c;
    if (lane == 63) wsum[wid] = inc;
    __syncthreads();
    int wavePre = 0;
    #pragma unroll
    for (int w = 0; w < 4; ++w) if (w < wid) wavePre += wsum[w];
    const int total = wsum[0] + wsum[1] + wsum[2] + wsum[3];
    int pos = base + wavePre + lanePre;
    __syncthreads();                 // all threads have read base & wsum
    if (t == 0) base += total;
    float4 tw = *(const float4*)&tokTopW[i0];
    if (f0) { toklist[e * 4096 + pos] = i0 >> 2;       wlist[e * 4096 + pos] = tw.x; posOf[i0]     = pos; pos++; }
    if (f1) { toklist[e * 4096 + pos] = (i0 + 1) >> 2; wlist[e * 4096 + pos] = tw.y; posOf[i0 + 1] = pos; pos++; }
    if (f2) { toklist[e * 4096 + pos] = (i0 + 2) >> 2; wlist[e * 4096 + pos] = tw.z; posOf[i0 + 2] = pos; pos++; }
    if (f3) { toklist[e * 4096 + pos] = (i0 + 3) >> 2; wlist[e * 4096 + pos] = tw.w; posOf[i0 + 3] = pos; pos++; }
  }
  __syncthreads();
  if (t == 0) cnt[e] = base;
}

__global__ void finalize_router_kernel(const int* __restrict__ cnt,
                                       int* __restrict__ baseOff,
                                       float* __restrict__ aux) {
  if (threadIdx.x == 0 && blockIdx.x == 0) {
    int s = 0;
    for (int e = 0; e < 16; ++e) { baseOff[e] = s; s += cnt[e]; }
    aux[0] = 16.0f;  // both load-balance fractions sum to 1 exactly
  }
}

// ---------------- merged gate/up GEMM (shared + routed in ONE dispatch) -----------
// z in [0,16): routed expert z, gathered A rows, B = gate_up_proj[z], out act_e.
// z in [16,20): shared expert, colBlk = (z-16)*8 + bx, B = sg/su, out act_s.
// K = 1024 for both. B tile interleaves gate(even)/up(odd); epilogue pairs lane^1.
// LDS swizzle: linear dest, pre-swizzled global source, XOR'd ds_read (T2+rule21).
__global__ __launch_bounds__(256, 4)
void gateup_merged_kernel(const bf16_t* __restrict__ h_bf,
                          const bf16_t* __restrict__ gup_bf,
                          const bf16_t* __restrict__ sg_bf,
                          const bf16_t* __restrict__ su_bf,
                          bf16_t* __restrict__ act_e,
                          bf16_t* __restrict__ act_s,
                          const int* __restrict__ cnt,
                          const int* __restrict__ baseOff,
                          const int* __restrict__ toklist) {
  const int z = blockIdx.z;
  const int rowBlk = blockIdx.y;
  const bool routed = (z < 16);

  int M, actRowBase, colBlk, ldAct;
  const bf16_t *b1, *b2;
  const int* gather;
  bf16_t* actOut;
  if (routed) {
    M = cnt[z];
    if (rowBlk * 128 >= M) return;
    actRowBase = baseOff[z] + rowBlk * 128;
    colBlk = blockIdx.x;
    b1 = gup_bf + (size_t)z * 1048576;
    b2 = b1 + 524288;
    gather = toklist + z * 4096;
    actOut = act_e; ldAct = 512;
  } else {
    M = 4096;
    actRowBase = rowBlk * 128;
    colBlk = (z - 16) * 8 + blockIdx.x;
    b1 = sg_bf; b2 = su_bf;
    gather = nullptr;
    actOut = act_s; ldAct = 2048;
  }

  __shared__ __align__(16) bf16_t As[128 * 64];
  __shared__ __align__(16) bf16_t Bs[128 * 64];

  const int t = threadIdx.x;
  // swizzled source column granule: (t&7) XOR (tile-row & 7), 8 bf16 per granule
  const int sc = ((t & 7) ^ ((t >> 3) & 7)) * 8;

  const bf16_t* aSrc[4];
  const bf16_t* bSrc[4];
  #pragma unroll
  for (int i = 0; i < 4; ++i) {
    int r = (t >> 3) + 32 * i;  // tile row 0..127 (r&7 invariant in i)
    int rr = rowBlk * 128 + r;
    int grow = routed ? ((rr < M) ? gather[rr] : 0) : rr;
    aSrc[i] = h_bf + (size_t)grow * 1024 + sc;
    int j = colBlk * 64 + (r >> 1);
    bSrc[i] = ((r & 1) ? b2 : b1) + (size_t)j * 1024 + sc;
  }

  f32x4 acc[4][4];
  #pragma unroll
  for (int a = 0; a < 4; ++a)
    #pragma unroll
    for (int b = 0; b < 4; ++b)
      acc[a][b] = (f32x4){0.f, 0.f, 0.f, 0.f};

  const int lane = t & 63;
  const int wid = t >> 6;
  const int wm = wid >> 1, wn = wid & 1;
  const int lr = lane & 15;
  const int lk = (lane >> 4) * 8;

  bf16_t* aDst = As + t * 8;
  bf16_t* bDst = Bs + t * 8;

  for (int k0 = 0; k0 < 1024; k0 += 64) {
    #pragma unroll
    for (int i = 0; i < 4; ++i) gl_lds16(aSrc[i], aDst + i * 2048);
    #pragma unroll
    for (int i = 0; i < 4; ++i) gl_lds16(bSrc[i], bDst + i * 2048);
    #pragma unroll
    for (int i = 0; i < 4; ++i) { aSrc[i] += 64; bSrc[i] += 64; }
    __syncthreads();
    #pragma unroll
    for (int kk = 0; kk < 64; kk += 32) {
      bf16x8v af[4], bfr[4];
      #pragma unroll
      for (int f = 0; f < 4; ++f) {
        const int row = wm * 64 + f * 16 + lr;
        af[f] = *(const bf16x8v*)&As[row * 64 + ((kk + lk) ^ ((row & 7) << 3))];
      }
      #pragma unroll
      for (int f = 0; f < 4; ++f) {
        const int row = wn * 64 + f * 16 + lr;
        bfr[f] = *(const bf16x8v*)&Bs[row * 64 + ((kk + lk) ^ ((row & 7) << 3))];
      }
      #pragma unroll
      for (int fm = 0; fm < 4; ++fm)
        #pragma unroll
        for (int fn = 0; fn < 4; ++fn)
          acc[fm][fn] = __builtin_amdgcn_mfma_f32_16x16x32_bf16(
              af[fm], bfr[fn], acc[fm][fn], 0, 0, 0);
    }
    __syncthreads();
  }

  // epilogue: pair gate (even n) with up (odd n) via lane^1, write silu(g)*u
  const int mRem = M - rowBlk * 128;
  #pragma unroll
  for (int fm = 0; fm < 4; ++fm) {
    #pragma unroll
    for (int fn = 0; fn < 4; ++fn) {
      const int nloc = wn * 64 + fn * 16 + lr;
      const int j = colBlk * 64 + (nloc >> 1);
      const bool even = (nloc & 1) == 0;
      #pragma unroll
      for (int r = 0; r < 4; ++r) {
        float mine = acc[fm][fn][r];
        float other = __shfl_xor(mine, 1);
        float gate = even ? mine : other;
        float up = even ? other : mine;
        float act = fast_silu(gate) * up;
        int tr = wm * 64 + fm * 16 + (lane >> 4) * 4 + r;
        if (even && tr < mRem)
          actOut[(size_t)(actRowBase + tr) * ldAct + j] = (bf16_t)act;
      }
    }
  }
}

// ---------------- merged down GEMM (shared + routed in ONE dispatch) --------------
// z in [0,16): routed expert z: K=512, A=act_e slice, out = dsc bf16 (w pre-applied).
// z == 16:     shared: K=2048, A=act_s, out = f32 sigmoid(gate)*acc into `out`.
__global__ __launch_bounds__(256, 4)
void down_merged_kernel(const bf16_t* __restrict__ act_e,
                        const bf16_t* __restrict__ act_s,
                        const bf16_t* __restrict__ dwn_bf,
                        const bf16_t* __restrict__ sd_bf,
                        float* __restrict__ outF,
                        bf16_t* __restrict__ dsc,
                        const float* __restrict__ gsig,
                        const int* __restrict__ cnt,
                        const int* __restrict__ baseOff,
                        const float* __restrict__ wlist) {
  const int z = blockIdx.z;
  const int rowBlk = blockIdx.y, colBlk = blockIdx.x;
  const bool routed = (z < 16);

  int M, K, aRowBase;
  const bf16_t *A, *B;
  if (routed) {
    M = cnt[z];
    if (rowBlk * 128 >= M) return;
    K = 512;
    aRowBase = baseOff[z] + rowBlk * 128;
    A = act_e + (size_t)baseOff[z] * 512;
    B = dwn_bf + (size_t)z * 524288;
  } else {
    M = 4096; K = 2048;
    aRowBase = rowBlk * 128;
    A = act_s;
    B = sd_bf;
  }

  __shared__ __align__(16) bf16_t As[128 * 64];
  __shared__ __align__(16) bf16_t Bs[128 * 64];

  const int t = threadIdx.x;
  const int sc = ((t & 7) ^ ((t >> 3) & 7)) * 8;
  const bf16_t* aSrc[4];
  const bf16_t* bSrc[4];
  #pragma unroll
  for (int i = 0; i < 4; ++i) {
    int r = (t >> 3) + 32 * i;
    aSrc[i] = A + (size_t)(rowBlk * 128 + r) * K + sc;
    bSrc[i] = B + (size_t)(colBlk * 128 + r) * K + sc;
  }

  f32x4 acc[4][4];
  #pragma unroll
  for (int a = 0; a < 4; ++a)
    #pragma unroll
    for (int b = 0; b < 4; ++b)
      acc[a][b] = (f32x4){0.f, 0.f, 0.f, 0.f};

  const int lane = t & 63;
  const int wid = t >> 6;
  const int wm = wid >> 1, wn = wid & 1;
  const int lr = lane & 15;
  const int lk = (lane >> 4) * 8;

  bf16_t* aDst = As + t * 8;
  bf16_t* bDst = Bs + t * 8;

  for (int k0 = 0; k0 < K; k0 += 64) {
    #pragma unroll
    for (int i = 0; i < 4; ++i) gl_lds16(aSrc[i], aDst + i * 2048);
    #pragma unroll
    for (int i = 0; i < 4; ++i) gl_lds16(bSrc[i], bDst + i * 2048);
    #pragma unroll
    for (int i = 0; i < 4; ++i) { aSrc[i] += 64; bSrc[i] += 64; }
    __syncthreads();
    #pragma unroll
    for (int kk = 0; kk < 64; kk += 32) {
      bf16x8v af[4], bfr[4];
      #pragma unroll
      for (int f = 0; f < 4; ++f) {
        const int row = wm * 64 + f * 16 + lr;
        af[f] = *(const bf16x8v*)&As[row * 64 + ((kk + lk) ^ ((row & 7) << 3))];
      }
      #pragma unroll
      for (int f = 0; f < 4; ++f) {
        const int row = wn * 64 + f * 16 + lr;
        bfr[f] = *(const bf16x8v*)&Bs[row * 64 + ((kk + lk) ^ ((row & 7) << 3))];
      }
      #pragma unroll
      for (int fm = 0; fm < 4; ++fm)
        #pragma unroll
        for (int fn = 0; fn < 4; ++fn)
          acc[fm][fn] = __builtin_amdgcn_mfma_f32_16x16x32_bf16(
              af[fm], bfr[fn], acc[fm][fn], 0, 0, 0);
    }
    __syncthreads();
  }

  const int mRem = M - rowBlk * 128;
  #pragma unroll
  for (int fm = 0; fm < 4; ++fm) {
    #pragma unroll
    for (int r = 0; r < 4; ++r) {
      const int tr = wm * 64 + fm * 16 + (lane >> 4) * 4 + r;
      if (tr < mRem) {
        float wgt;
        if (routed) wgt = wlist[z * 4096 + rowBlk * 128 + tr];
        else        wgt = gsig[rowBlk * 128 + tr];
        #pragma unroll
        for (int fn = 0; fn < 4; ++fn) {
          const int col = colBlk * 128 + wn * 64 + fn * 16 + lr;
          float v = acc[fm][fn][r] * wgt;
          if (routed)
            dsc[(size_t)(aRowBase + tr) * 1024 + col] = (bf16_t)v;
          else
            outF[(size_t)(aRowBase + tr) * 1024 + col] = v;
        }
      }
    }
  }
}

// ---------------- combine: out[tok] += sum of the token's 4 expert rows ----------
__global__ __launch_bounds__(256)
void combine_kernel(const bf16_t* __restrict__ dsc,
                    const int* __restrict__ tokTopI,
                    const int* __restrict__ posOf,
                    const int* __restrict__ baseOff,
                    float* __restrict__ out) {
  const int tok = blockIdx.x;
  const int t = threadIdx.x;
  __shared__ const bf16_t* rows[4];
  if (t < 4) {
    int e = tokTopI[tok * 4 + t];
    rows[t] = dsc + (size_t)(baseOff[e] + posOf[tok * 4 + t]) * 1024;
  }
  __syncthreads();
  float4* orow = (float4*)(out + (size_t)tok * 1024);
  float4 v = orow[t];
  #pragma unroll
  for (int k = 0; k < 4; ++k) {
    bf16x4v b = *(const bf16x4v*)(rows[k] + t * 4);
    v.x += (float)b[0]; v.y += (float)b[1]; v.z += (float)b[2]; v.w += (float)b[3];
  }
  orow[t] = v;
}

// ---------------- workspace layout (bytes) ----------------
// h_bf     @ 0          8,388,608
// gup_bf   @ 8388608    33,554,432   (reused as dsc[16384*1024 bf16] after gateup)
// dwn_bf   @ 41943040   16,777,216
// sg_bf    @ 58720256   4,194,304
// su_bf    @ 62914560   4,194,304
// sd_bf    @ 67108864   4,194,304
// act_s    @ 71303168   16,777,216
// act_e    @ 88080384   16,777,216   (+256KB overread pad before gsig)
// gsig     @ 105119744  16,384
// cnt      @ 105136128  64
// base     @ 105136384  64
// toklist  @ 105136640  262,144
// wlist    @ 105398784  262,144
// tokTopI  @ 105660928  65,536
// tokTopW  @ 105726464  65,536
// posOf    @ 105791744  65,536      total ~105.9 MB

extern "C" void kernel_launch(void* const* d_in, const int* in_sizes, int n_in,
                              void* d_out, int out_size, void* d_ws, size_t ws_size,
                              hipStream_t stream) {
  const float* h_f32 = (const float*)d_in[0];
  const float* rw    = (const float*)d_in[1];
  const float* gup   = (const float*)d_in[2];
  const float* dwn   = (const float*)d_in[3];
  const float* sgate = (const float*)d_in[4];
  const float* sup   = (const float*)d_in[5];
  const float* sdown = (const float*)d_in[6];
  const float* segw  = (const float*)d_in[7];

  char* ws = (char*)d_ws;
  bf16_t* h_bf    = (bf16_t*)(ws + 0);
  bf16_t* gup_bf  = (bf16_t*)(ws + 8388608);
  bf16_t* dwn_bf  = (bf16_t*)(ws + 41943040);
  bf16_t* sg_bf   = (bf16_t*)(ws + 58720256);
  bf16_t* su_bf   = (bf16_t*)(ws + 62914560);
  bf16_t* sd_bf   = (bf16_t*)(ws + 67108864);
  bf16_t* act_s   = (bf16_t*)(ws + 71303168);
  bf16_t* act_e   = (bf16_t*)(ws + 88080384);
  float*  gsig    = (float*)(ws + 105119744);
  int*    cnt     = (int*)(ws + 105136128);
  int*    baseOff = (int*)(ws + 105136384);
  int*    toklist = (int*)(ws + 105136640);
  float*  wlist   = (float*)(ws + 105398784);
  int*    tokTopI = (int*)(ws + 105660928);
  float*  tokTopW = (float*)(ws + 105726464);
  int*    posOf   = (int*)(ws + 105791744);
  bf16_t* dsc     = gup_bf;  // 32MB; gateup (last gup reader) precedes down (writer)

  float* out = (float*)d_out;
  float* aux = out + 4194304;

  cvt_all_kernel<<<4096, 256, 0, stream>>>(h_f32, gup, dwn, sgate, sup, sdown,
                                           h_bf, gup_bf, dwn_bf, sg_bf, su_bf, sd_bf);

  router_topk_kernel<<<256, 256, 0, stream>>>(h_f32, rw, segw, gsig, tokTopI, tokTopW);
  build_lists_kernel<<<16, 256, 0, stream>>>(tokTopI, tokTopW, cnt, toklist, wlist, posOf);
  finalize_router_kernel<<<1, 64, 0, stream>>>(cnt, baseOff, aux);

  // one dispatch: z<16 routed gate/up (gathered), z in 16..19 shared gate/up
  gateup_merged_kernel<<<dim3(8, 32, 20), 256, 0, stream>>>(
      h_bf, gup_bf, sg_bf, su_bf, act_e, act_s, cnt, baseOff, toklist);

  // one dispatch: z<16 routed down -> dsc (bf16, weighted), z=16 shared down -> out
  down_merged_kernel<<<dim3(8, 32, 17), 256, 0, stream>>>(
      act_e, act_s, dwn_bf, sd_bf, out, dsc, gsig, cnt, baseOff, wlist);

  // gather the 4 rows per token and add into out
  combine_kernel<<<4096, 256, 0, stream>>>(dsc, tokTopI, posOf, baseOff, out);
}